// Round 1
// baseline (286.755 us; speedup 1.0000x reference)
//
#include <hip/hip_runtime.h>

// One thread per (batch, edge). Memory-bound: 64B feat + 4B base read + 4B out
// per edge => ~230 MB total => ~37us floor at 6.3 TB/s.
__global__ __launch_bounds__(256) void ConditionalEdgeMasker_kernel(
    const float* __restrict__ feat,   // (B, E, 16)
    const float* __restrict__ phys,   // (B, 18)
    const float* __restrict__ base,   // (B, E)
    float* __restrict__ out,          // (B, E)
    int E)
{
    const int b = blockIdx.y;
    const int e = blockIdx.x * blockDim.x + threadIdx.x;
    if (e >= E) return;

    // Per-batch physics scalars (broadcast load, L1-cached).
    const float* p = phys + (size_t)b * 18;
    const float vel  = p[2];
    const float wall = p[5];
    const float ke   = p[9];
    const float cj   = p[16];
    const float cwj  = p[17];

    // Batch-uniform sub-conditions (hoisted; wave-uniform per blockIdx.y).
    const bool cj_low   = cj < 0.5f;
    const bool wall_low = wall < 0.5f;
    const bool d2 = wall_low || (vel < 0.1f);
    // precedence: | over (& of two) -> wall_low | ((cwj<0.5) & (vel<1.0))
    const bool d4 = wall_low || ((cwj < 0.5f) && (vel < 1.0f));

    const size_t idx = (size_t)b * E + e;
    const float4* f4 = (const float4*)(feat + idx * 16);
    const float4 a0 = f4[0];  // cols 0..3
    const float4 a1 = f4[1];  // cols 4..7
    const float4 a2 = f4[2];  // cols 8..11 (need col 10)
    const float4 a3 = f4[3];  // cols 12..15

    // argmax over cols 0..5, first occurrence of max -> strict '>'
    int   et = 0;
    float m  = a0.x;
    if (a0.y > m) { m = a0.y; et = 1; }
    if (a0.z > m) { m = a0.z; et = 2; }
    if (a0.w > m) { m = a0.w; et = 3; }
    if (a1.x > m) { m = a1.x; et = 4; }
    if (a1.y > m) { m = a1.y; et = 5; }

    const float energy_cost = a2.z;  // col 10
    const float min_v  = a3.x;       // col 12
    const float max_v  = a3.y;       // col 13
    const float req_j  = a3.z;       // col 14
    const float req_wc = a3.w;       // col 15

    // jnp.select: ordered condition chain, default false.
    bool disable;
    if (et == 1 && cj_low)       disable = true;                       // c1
    else if (et == 3)            disable = d2;                         // c2
    else if (req_j > 0.5f)       disable = cj_low || (vel < min_v);    // c3
    else if (req_wc > 0.5f)      disable = d4;                        // c4
    else if (et == 1)            disable = (ke < energy_cost * 0.5f);  // c5
    else                         disable = false;

    const bool over  = (max_v > 0.0f) && (vel > max_v);
    const bool under = (!over) && (vel < min_v);
    disable = disable || over || under;

    out[idx] = disable ? 0.0f : base[idx];
}

extern "C" void kernel_launch(void* const* d_in, const int* in_sizes, int n_in,
                              void* d_out, int out_size, void* d_ws, size_t ws_size,
                              hipStream_t stream) {
    const float* feat = (const float*)d_in[0];
    const float* phys = (const float*)d_in[1];
    const float* base = (const float*)d_in[2];
    float* out = (float*)d_out;

    const int B = in_sizes[1] / 18;          // ninja_physics_state is (B, 18)
    const int E = in_sizes[2] / B;           // base_edge_mask is (B, E)

    dim3 block(256);
    dim3 grid((E + 255) / 256, B);
    ConditionalEdgeMasker_kernel<<<grid, block, 0, stream>>>(feat, phys, base, out, E);
}